// Round 1
// baseline (640.775 us; speedup 1.0000x reference)
//
#include <hip/hip_runtime.h>
#include <hip/hip_bf16.h>
#include <stdint.h>

#define NA 131072
#define HD 256
#define NF 4096
#define MINFRAG 3
#define LN_EPS 1e-5f
#define NEPS 1e-12f

// ---- workspace layout (bytes) ----
#define OFF_SSUM   0ull                    // NF*HD f32 = 4194304
#define OFF_CNT    4194304ull              // NF i32
#define OFF_VSUM   4210688ull              // NF f32 (sum of vec_mag)
#define OFF_VFSUM  4227072ull              // NF f32 (sum of silu(vec_mag*w0))
#define OFF_DBL    4243456ull              // 261 doubles: sumc[257],trace,devS,devV,validCnt
#define ZERO_BYTES 4245544ull
#define OFF_FRAGC  4245760ull              // NF f32
#define OFF_VSIGN  4262144ull              // NF f32
#define OFF_GT     4278528ull              // HD*HD f32, Gt[h][o] = gamma[h]*W1[o][h]
#define OFF_SVEC   4540672ull              // HD f32
#define OFF_C0     4541696ull              // HD f32
#define OFF_W0     4542720ull              // 1 f32
#define OFF_MU     4542976ull              // NA f32
#define OFF_RSIG   5067264ull              // NA f32
#define OFF_VMAG   5591552ull              // NA f32
#define OFF_FEAT   6115840ull              // NA*HD bf16 = 67108864
// total ws needed: 73224704 bytes (~70 MB)

#define IDX_TRACE 257
#define IDX_DEVS  258
#define IDX_DEVV  259
#define IDX_VCNT  260

__device__ __forceinline__ float wredsum(float v) {
#pragma unroll
    for (int m = 32; m; m >>= 1) v += __shfl_xor(v, m, 64);
    return v;
}

__device__ __forceinline__ float silu_f(float x) {
    return x / (1.f + expf(-x));
}

// ---------------- prep: Gt = gamma*W1^T layout, svec, c0, w0 ----------------
__global__ __launch_bounds__(256) void k_prep(
    const float* __restrict__ W1, const float* __restrict__ gamma,
    const float* __restrict__ beta, const float* __restrict__ b1,
    const float* __restrict__ Wv,
    float* __restrict__ Gt, float* __restrict__ svec, float* __restrict__ c0,
    float* __restrict__ w0) {
    __shared__ float red[8];
    int o = blockIdx.x;
    int t = threadIdx.x;  // == h
    if (o < HD) {
        float w = W1[(size_t)o * HD + t];
        float g = w * gamma[t];
        Gt[(size_t)t * HD + o] = g;  // transposed store
        float sp = g;
        float cp = w * beta[t];
#pragma unroll
        for (int m = 32; m; m >>= 1) { sp += __shfl_xor(sp, m, 64); cp += __shfl_xor(cp, m, 64); }
        int wv = t >> 6;
        if ((t & 63) == 0) { red[wv] = sp; red[4 + wv] = cp; }
        __syncthreads();
        if (t == 0) {
            svec[o] = red[0] + red[1] + red[2] + red[3];
            c0[o]   = red[4] + red[5] + red[6] + red[7] + b1[o];
        }
    } else {
        float v = Wv[t];  // row 0 of Wv
#pragma unroll
        for (int m = 32; m; m >>= 1) v += __shfl_xor(v, m, 64);
        int wv = t >> 6;
        if ((t & 63) == 0) red[wv] = v;
        __syncthreads();
        if (t == 0) w0[0] = red[0] + red[1] + red[2] + red[3];
    }
}

// ---------------- stats: mu/rsig, vec_mag, histogram + frag scalar sums ----
__global__ __launch_bounds__(256) void k_stats(
    const float* __restrict__ ss, const float* __restrict__ vs,
    const int* __restrict__ fid, const float* __restrict__ w0p,
    float* __restrict__ mu, float* __restrict__ rsig, float* __restrict__ vmag,
    int* __restrict__ cnt, float* __restrict__ vsum, float* __restrict__ vfsum) {
    int gwave = (blockIdx.x * blockDim.x + threadIdx.x) >> 6;
    int lane = threadIdx.x & 63;
    int nw = (gridDim.x * blockDim.x) >> 6;
    float w0 = w0p[0];
    for (int i = gwave; i < NA; i += nw) {
        float4 x = ((const float4*)(ss + (size_t)i * HD))[lane];
        float s1 = x.x + x.y + x.z + x.w;
        float s2 = x.x * x.x + x.y * x.y + x.z * x.z + x.w * x.w;
        s1 = wredsum(s1);
        s2 = wredsum(s2);
        float m_ = s1 * (1.f / HD);
        float var = s2 * (1.f / HD) - m_ * m_;
        float rs = rsqrtf(var + LN_EPS);
        float nsum = 0.f;
#pragma unroll
        for (int c = 0; c < 3; ++c) {
            float4 v = ((const float4*)(vs + ((size_t)i * 3 + c) * HD))[lane];
            float q = v.x * v.x + v.y * v.y + v.z * v.z + v.w * v.w;
            q = wredsum(q);
            nsum += sqrtf(q);
        }
        if (lane == 0) {
            mu[i] = m_;
            rsig[i] = rs;
            float vm = nsum * (1.f / 3.f);
            vmag[i] = vm;
            float vf = silu_f(vm * w0);
            int f = fid[i];
            atomicAdd(&cnt[f], 1);
            atomicAdd(&vsum[f], vm);
            atomicAdd(&vfsum[f], vf);
        }
    }
}

// ---------------- GEMM: feat = silu(LN(x) @ W1^T + b1), fused epilogue -----
#define BM 64
#define BK 32
__global__ __launch_bounds__(256) void k_gemm(
    const float* __restrict__ A, const float* __restrict__ Gt,
    const float* __restrict__ mu, const float* __restrict__ rsig,
    const float* __restrict__ svec, const float* __restrict__ c0,
    const int* __restrict__ fid,
    __hip_bfloat16* __restrict__ feat, float* __restrict__ ssum) {
    __shared__ float As[BM][BK + 4];   // pad 4 keeps float4 alignment, 2-way banks (free)
    __shared__ float Bs[BK * HD];      // Bs[k][o]

    int tid = threadIdx.x;
    int tx = tid & 31, ty = tid >> 5;
    int blockRow = blockIdx.x * BM;

    float acc[8][8] = {};

    int la_r = tid >> 2;
    int la_c = (tid & 3) * 8;
    const float* Aptr = A + (size_t)(blockRow + la_r) * HD + la_c;

    for (int k0 = 0; k0 < HD; k0 += BK) {
        __syncthreads();
        *(float4*)&As[la_r][la_c]     = *(const float4*)(Aptr + k0);
        *(float4*)&As[la_r][la_c + 4] = *(const float4*)(Aptr + k0 + 4);
#pragma unroll
        for (int p = 0; p < 8; ++p) {
            int flat = p * 1024 + tid * 4;
            *(float4*)&Bs[flat] = *(const float4*)(Gt + (size_t)k0 * HD + flat);
        }
        __syncthreads();
#pragma unroll
        for (int kk4 = 0; kk4 < 8; ++kk4) {
            float4 a4[8];
#pragma unroll
            for (int i = 0; i < 8; ++i) a4[i] = *(const float4*)&As[ty * 8 + i][kk4 * 4];
#pragma unroll
            for (int e = 0; e < 4; ++e) {
                int kk = kk4 * 4 + e;
                float b[8];
#pragma unroll
                for (int j = 0; j < 8; ++j) b[j] = Bs[kk * HD + tx + 32 * j];
                float a_[8];
#pragma unroll
                for (int i = 0; i < 8; ++i)
                    a_[i] = (e == 0) ? a4[i].x : (e == 1) ? a4[i].y : (e == 2) ? a4[i].z : a4[i].w;
#pragma unroll
                for (int i = 0; i < 8; ++i)
#pragma unroll
                    for (int j = 0; j < 8; ++j) acc[i][j] = fmaf(a_[i], b[j], acc[i][j]);
            }
        }
    }

    float sv[8], cv[8];
#pragma unroll
    for (int j = 0; j < 8; ++j) {
        int c = tx + 32 * j;
        sv[j] = svec[c];
        cv[j] = c0[c];
    }
#pragma unroll
    for (int i = 0; i < 8; ++i) {
        int arow = blockRow + ty * 8 + i;
        float mu_i = mu[arow];
        float rs_i = rsig[arow];
        int f = fid[arow];
#pragma unroll
        for (int j = 0; j < 8; ++j) {
            int c = tx + 32 * j;
            float pre = rs_i * (acc[i][j] - mu_i * sv[j]) + cv[j];
            float ft = silu_f(pre);
            feat[(size_t)arow * HD + c] = __float2bfloat16(ft);
            atomicAdd(&ssum[(size_t)f * HD + c], ft);
        }
    }
}

// ---------------- fragment pass: coefs + normalized-row accumulation -------
__global__ __launch_bounds__(256) void k_frag(
    const float* __restrict__ ssum, const int* __restrict__ cnt,
    const float* __restrict__ vsum, const float* __restrict__ vfsum,
    float* __restrict__ fragcoef, float* __restrict__ vsign,
    double* __restrict__ dbl) {
    int gwave = (blockIdx.x * blockDim.x + threadIdx.x) >> 6;
    int lane = threadIdx.x & 63;
    int nw = (gridDim.x * blockDim.x) >> 6;

    double la0 = 0, la1 = 0, la2 = 0, la3 = 0;  // sumc dims 4*lane..+3
    double lv = 0, ltr = 0, lvc = 0;            // sumc[256], trace, validCnt

    for (int f = gwave; f < NF; f += nw) {
        float4 v = ((const float4*)(ssum + (size_t)f * HD))[lane];
        int c = cnt[f];
        float inv_all = 1.f / fmaxf((float)c, 1.f);
        float m0 = v.x * inv_all, m1 = v.y * inv_all, m2 = v.z * inv_all, m3 = v.w * inv_all;
        float ssq = wredsum(m0 * m0 + m1 * m1 + m2 * m2 + m3 * m3);
        float vfr = vsum[f] * inv_all;
        float nrm2 = ssq + vfr * vfr;
        float inv = 1.f / fmaxf(sqrtf(nrm2), NEPS);
        la0 += (double)(m0 * inv);
        la1 += (double)(m1 * inv);
        la2 += (double)(m2 * inv);
        la3 += (double)(m3 * inv);
        if (lane == 0) {
            lv += (double)(vfr * inv);
            ltr += (double)(nrm2 * inv * inv);
            if (c >= MINFRAG) {
                fragcoef[f] = 1.f / ((float)c * fmaxf(sqrtf(ssq), NEPS));
                float ms = vfsum[f] / (float)c;
                vsign[f] = ms / fmaxf(fabsf(ms), NEPS);
                lvc += (double)c;
            } else {
                fragcoef[f] = 0.f;
                vsign[f] = 0.f;
            }
        }
    }
    atomicAdd(&dbl[4 * lane + 0], la0);
    atomicAdd(&dbl[4 * lane + 1], la1);
    atomicAdd(&dbl[4 * lane + 2], la2);
    atomicAdd(&dbl[4 * lane + 3], la3);
    if (lane == 0) {
        atomicAdd(&dbl[256], lv);
        atomicAdd(&dbl[IDX_TRACE], ltr);
        atomicAdd(&dbl[IDX_VCNT], lvc);
    }
}

// ---------------- deviation pass ----------------
__global__ __launch_bounds__(256) void k_dev(
    const __hip_bfloat16* __restrict__ feat, const float* __restrict__ ssum,
    const int* __restrict__ fid, const int* __restrict__ cnt,
    const float* __restrict__ fragcoef, const float* __restrict__ vsign,
    const float* __restrict__ vmag, const float* __restrict__ w0p,
    double* __restrict__ dbl) {
    int gwave = (blockIdx.x * blockDim.x + threadIdx.x) >> 6;
    int lane = threadIdx.x & 63;
    int nw = (gridDim.x * blockDim.x) >> 6;
    float w0 = w0p[0];
    double accS = 0, accV = 0;
    for (int i = gwave; i < NA; i += nw) {
        int f = fid[i];
        ushort4 u = ((const ushort4*)(feat + (size_t)i * HD))[lane];
        float f0 = __uint_as_float(((uint32_t)u.x) << 16);
        float f1 = __uint_as_float(((uint32_t)u.y) << 16);
        float f2 = __uint_as_float(((uint32_t)u.z) << 16);
        float f3 = __uint_as_float(((uint32_t)u.w) << 16);
        float4 ms = ((const float4*)(ssum + (size_t)f * HD))[lane];
        float dot = f0 * ms.x + f1 * ms.y + f2 * ms.z + f3 * ms.w;
        float nf = f0 * f0 + f1 * f1 + f2 * f2 + f3 * f3;
        dot = wredsum(dot);
        nf = wredsum(nf);
        if (lane == 0 && cnt[f] >= MINFRAG) {
            float sim = dot * fragcoef[f] / fmaxf(sqrtf(nf), NEPS);
            accS += (double)(1.f - sim);
            float vf = silu_f(vmag[i] * w0);
            float nv = vf / fmaxf(fabsf(vf), NEPS);
            accV += (double)(1.f - nv * vsign[f]);
        }
    }
    if (lane == 0) {
        atomicAdd(&dbl[IDX_DEVS], accS);
        atomicAdd(&dbl[IDX_DEVV], accV);
    }
}

// ---------------- final combine ----------------
__global__ __launch_bounds__(256) void k_final(const double* __restrict__ dbl,
                                               float* __restrict__ out) {
    if (threadIdx.x == 0 && blockIdx.x == 0) {
        double s2 = 0;
        for (int d = 0; d < 257; ++d) s2 += dbl[d] * dbl[d];
        double off = s2 - dbl[IDX_TRACE];
        double inter = off / ((double)NF * NF - NF + 1e-6);
        double vc = fmax(dbl[IDX_VCNT], 1.0);
        double total = dbl[IDX_DEVS] / vc + dbl[IDX_DEVV] / vc + 0.2 * inter;
        out[0] = (float)(0.03 * 0.05 * total);
    }
}

extern "C" void kernel_launch(void* const* d_in, const int* in_sizes, int n_in,
                              void* d_out, int out_size, void* d_ws, size_t ws_size,
                              hipStream_t stream) {
    const float* scalar_short = (const float*)d_in[0];
    // d_in[1] scalar_long: unused
    const float* vector_short = (const float*)d_in[2];
    // d_in[3] vector_long: unused
    const int* fragment_ids = (const int*)d_in[4];
    const float* ln_gamma = (const float*)d_in[5];
    const float* ln_beta = (const float*)d_in[6];
    const float* W1 = (const float*)d_in[7];
    const float* b1 = (const float*)d_in[8];
    const float* Wv = (const float*)d_in[9];
    float* out = (float*)d_out;

    char* ws = (char*)d_ws;
    float* ssum = (float*)(ws + OFF_SSUM);
    int* cnt = (int*)(ws + OFF_CNT);
    float* vsum = (float*)(ws + OFF_VSUM);
    float* vfsum = (float*)(ws + OFF_VFSUM);
    double* dbl = (double*)(ws + OFF_DBL);
    float* fragcoef = (float*)(ws + OFF_FRAGC);
    float* vsign = (float*)(ws + OFF_VSIGN);
    float* Gt = (float*)(ws + OFF_GT);
    float* svec = (float*)(ws + OFF_SVEC);
    float* c0 = (float*)(ws + OFF_C0);
    float* w0 = (float*)(ws + OFF_W0);
    float* mu = (float*)(ws + OFF_MU);
    float* rsig = (float*)(ws + OFF_RSIG);
    float* vmag = (float*)(ws + OFF_VMAG);
    __hip_bfloat16* feat = (__hip_bfloat16*)(ws + OFF_FEAT);

    hipMemsetAsync(ws, 0, ZERO_BYTES, stream);
    k_prep<<<HD + 1, 256, 0, stream>>>(W1, ln_gamma, ln_beta, b1, Wv, Gt, svec, c0, w0);
    k_stats<<<2048, 256, 0, stream>>>(scalar_short, vector_short, fragment_ids, w0,
                                      mu, rsig, vmag, cnt, vsum, vfsum);
    k_gemm<<<NA / BM, 256, 0, stream>>>(scalar_short, Gt, mu, rsig, svec, c0,
                                        fragment_ids, feat, ssum);
    k_frag<<<64, 256, 0, stream>>>(ssum, cnt, vsum, vfsum, fragcoef, vsign, dbl);
    k_dev<<<2048, 256, 0, stream>>>(feat, ssum, fragment_ids, cnt, fragcoef, vsign,
                                    vmag, w0, dbl);
    k_final<<<1, 64, 0, stream>>>(dbl, out);
}

// Round 2
// 474.005 us; speedup vs baseline: 1.3518x; 1.3518x over previous
//
#include <hip/hip_runtime.h>
#include <hip/hip_bf16.h>
#include <stdint.h>

#define NA 131072
#define HD 256
#define NF 4096
#define MINFRAG 3
#define LN_EPS 1e-5f
#define NEPS 1e-12f

// ---- workspace layout (bytes) ----
// zeroed region first
#define OFF_CNT    0ull          // NF i32
#define OFF_VSUM   16384ull      // NF f32
#define OFF_VFSUM  32768ull      // NF f32
#define OFF_FILL   49152ull      // NF i32
#define OFF_DBL    65536ull      // 261 doubles
#define ZERO_BYTES 67624ull
// non-zeroed
#define OFF_OFFS   69632ull      // NF i32 (exclusive scan of cnt)
#define OFF_FRAGC  86016ull      // NF f32
#define OFF_VSIGN  102400ull     // NF f32
#define OFF_SVEC   118784ull     // HD f32
#define OFF_C0     119808ull     // HD f32
#define OFF_W0     120832ull     // 1 f32
#define OFF_VMAG   131072ull     // NA f32
#define OFF_ORDER  655360ull     // NA i32 (atom ids sorted by fragment)
#define OFF_GBF    1179648ull    // HD*HD bf16 bits: Gbf[o][h] = bf16(gamma[h]*W1[o][h])
#define OFF_SSUM   1310720ull    // NF*HD f32
#define OFF_FEAT   5505024ull    // NA*HD bf16
// total: 72,613,888 bytes

#define IDX_TRACE 257
#define IDX_DEVS  258
#define IDX_DEVV  259
#define IDX_VCNT  260

typedef __attribute__((ext_vector_type(8))) short short8;
typedef __attribute__((ext_vector_type(4))) float f32x4;
union F4S8 { float4 f; short8 s; };
union BFU { __hip_bfloat16 b; unsigned short u; };

__device__ __forceinline__ unsigned short f2b(float x) {
    BFU t; t.b = __float2bfloat16(x); return t.u;
}
__device__ __forceinline__ float b2f(unsigned short u) {
    return __uint_as_float(((uint32_t)u) << 16);
}
__device__ __forceinline__ float wredsum(float v) {
#pragma unroll
    for (int m = 32; m; m >>= 1) v += __shfl_xor(v, m, 64);
    return v;
}
__device__ __forceinline__ float silu_f(float x) { return x / (1.f + expf(-x)); }

// ---------------- prep: Gbf = bf16(gamma*W1) [o][h] layout, svec, c0, w0 ----
__global__ __launch_bounds__(256) void k_prep(
    const float* __restrict__ W1, const float* __restrict__ gamma,
    const float* __restrict__ beta, const float* __restrict__ b1,
    const float* __restrict__ Wv,
    unsigned short* __restrict__ Gbf, float* __restrict__ svec,
    float* __restrict__ c0, float* __restrict__ w0) {
    __shared__ float red[8];
    int o = blockIdx.x;
    int t = threadIdx.x;  // == h
    if (o < HD) {
        float w = W1[(size_t)o * HD + t];
        unsigned short gb = f2b(w * gamma[t]);
        Gbf[(size_t)o * HD + t] = gb;
        float sp = b2f(gb);          // svec consistent with rounded operand
        float cp = w * beta[t];
#pragma unroll
        for (int m = 32; m; m >>= 1) { sp += __shfl_xor(sp, m, 64); cp += __shfl_xor(cp, m, 64); }
        int wv = t >> 6;
        if ((t & 63) == 0) { red[wv] = sp; red[4 + wv] = cp; }
        __syncthreads();
        if (t == 0) {
            svec[o] = red[0] + red[1] + red[2] + red[3];
            c0[o]   = red[4] + red[5] + red[6] + red[7] + b1[o];
        }
    } else {
        float v = Wv[t];  // row 0 of Wv
#pragma unroll
        for (int m = 32; m; m >>= 1) v += __shfl_xor(v, m, 64);
        int wv = t >> 6;
        if ((t & 63) == 0) red[wv] = v;
        __syncthreads();
        if (t == 0) w0[0] = red[0] + red[1] + red[2] + red[3];
    }
}

// ---------------- stats: vec_mag + fragment count/vec sums (vector only) ---
__global__ __launch_bounds__(256) void k_stats(
    const float* __restrict__ vs, const int* __restrict__ fid,
    const float* __restrict__ w0p,
    float* __restrict__ vmag, int* __restrict__ cnt,
    float* __restrict__ vsum, float* __restrict__ vfsum) {
    int gwave = (blockIdx.x * blockDim.x + threadIdx.x) >> 6;
    int lane = threadIdx.x & 63;
    int nw = (gridDim.x * blockDim.x) >> 6;
    float w0 = w0p[0];
    for (int i = gwave; i < NA; i += nw) {
        float nsum = 0.f;
#pragma unroll
        for (int c = 0; c < 3; ++c) {
            float4 v = ((const float4*)(vs + ((size_t)i * 3 + c) * HD))[lane];
            float q = v.x * v.x + v.y * v.y + v.z * v.z + v.w * v.w;
            q = wredsum(q);
            nsum += sqrtf(q);
        }
        if (lane == 0) {
            float vm = nsum * (1.f / 3.f);
            vmag[i] = vm;
            int f = fid[i];
            atomicAdd(&cnt[f], 1);
            atomicAdd(&vsum[f], vm);
            atomicAdd(&vfsum[f], silu_f(vm * w0));
        }
    }
}

// ---------------- scan: offs = exclusive prefix of cnt ---------------------
__global__ __launch_bounds__(256) void k_scan(const int* __restrict__ cnt,
                                              int* __restrict__ offs) {
    __shared__ int wsum[4];
    int t = threadIdx.x;
    int base = t * 16;
    int c[16];
    int tot = 0;
#pragma unroll
    for (int j = 0; j < 16; ++j) { c[j] = cnt[base + j]; tot += c[j]; }
    int lane = t & 63, w = t >> 6;
    int v = tot;
#pragma unroll
    for (int d = 1; d < 64; d <<= 1) {
        int o = __shfl_up(v, d, 64);
        if (lane >= d) v += o;
    }
    if (lane == 63) wsum[w] = v;
    __syncthreads();
    int wbase = 0;
    for (int i = 0; i < w; ++i) wbase += wsum[i];
    int run = wbase + v - tot;  // exclusive prefix for this thread
#pragma unroll
    for (int j = 0; j < 16; ++j) { offs[base + j] = run; run += c[j]; }
}

// ---------------- scatter: counting-sort atom ids by fragment --------------
__global__ __launch_bounds__(256) void k_scatter(
    const int* __restrict__ fid, const int* __restrict__ offs,
    int* __restrict__ fill, int* __restrict__ order) {
    int i = blockIdx.x * blockDim.x + threadIdx.x;
    if (i < NA) {
        int f = fid[i];
        int p = atomicAdd(&fill[f], 1);
        order[offs[f] + p] = i;
    }
}

// ---------------- GEMM: feat = silu(LN(x) @ (gamma*W1)^T + c0), MFMA -------
__global__ __launch_bounds__(256) void k_gemm(
    const float* __restrict__ A, const unsigned short* __restrict__ Gbf,
    const float* __restrict__ svec, const float* __restrict__ c0,
    unsigned short* __restrict__ feat) {
    __shared__ float4 As16[64 * 8];    // 64 rows x 64k bf16, xor-swizzled
    __shared__ float4 Bs16[256 * 8];   // 256 cols x 64k bf16, xor-swizzled
    __shared__ float muS[64], rsS[64];

    int tid = threadIdx.x;
    int lane = tid & 63, wid = tid >> 6;
    int r0 = blockIdx.x * 64;
    int rowT = tid >> 4;   // 0..15
    int c4 = tid & 15;

    f32x4 acc[4][4] = {};
    float s1p[4] = {0, 0, 0, 0}, s2p[4] = {0, 0, 0, 0};

    for (int k0 = 0; k0 < HD; k0 += 64) {
        // stage A (f32 -> bf16, + LN partial sums)
#pragma unroll
        for (int p = 0; p < 4; ++p) {
            int row = 16 * p + rowT;
            float4 v = *(const float4*)(A + (size_t)(r0 + row) * HD + k0 + c4 * 4);
            s1p[p] += v.x + v.y + v.z + v.w;
            s2p[p] += v.x * v.x + v.y * v.y + v.z * v.z + v.w * v.w;
            ushort4 pk;
            pk.x = f2b(v.x); pk.y = f2b(v.y); pk.z = f2b(v.z); pk.w = f2b(v.w);
            int slot = row * 8 + ((c4 >> 1) ^ (row & 7));
            ((ushort4*)&As16[slot])[c4 & 1] = pk;
        }
        // stage B (already bf16, L2-resident)
#pragma unroll
        for (int p = 0; p < 8; ++p) {
            int u = p * 256 + tid;
            int n = u >> 3, cc = u & 7;
            float4 g = *(const float4*)(Gbf + (size_t)n * HD + k0 + cc * 8);
            Bs16[n * 8 + (cc ^ (n & 7))] = g;
        }
        __syncthreads();
#pragma unroll
        for (int kk = 0; kk < 2; ++kk) {
            int uo = kk * 4 + (lane >> 4);
            short8 a[4], b[4];
#pragma unroll
            for (int mi = 0; mi < 4; ++mi) {
                int r = mi * 16 + (lane & 15);
                F4S8 t_; t_.f = As16[r * 8 + (uo ^ (r & 7))];
                a[mi] = t_.s;
            }
#pragma unroll
            for (int ni = 0; ni < 4; ++ni) {
                int n = wid * 64 + ni * 16 + (lane & 15);
                F4S8 t_; t_.f = Bs16[n * 8 + (uo ^ (n & 7))];
                b[ni] = t_.s;
            }
#pragma unroll
            for (int mi = 0; mi < 4; ++mi)
#pragma unroll
                for (int ni = 0; ni < 4; ++ni)
                    acc[mi][ni] = __builtin_amdgcn_mfma_f32_16x16x32_bf16(
                        a[mi], b[ni], acc[mi][ni], 0, 0, 0);
        }
        __syncthreads();
    }
    // finish LN stats: reduce within each 16-thread row group
#pragma unroll
    for (int p = 0; p < 4; ++p) {
        float s1 = s1p[p], s2 = s2p[p];
#pragma unroll
        for (int m = 1; m < 16; m <<= 1) {
            s1 += __shfl_xor(s1, m, 64);
            s2 += __shfl_xor(s2, m, 64);
        }
        if (c4 == 0) {
            int row = 16 * p + rowT;
            float mu_ = s1 * (1.f / HD);
            float var = s2 * (1.f / HD) - mu_ * mu_;
            muS[row] = mu_;
            rsS[row] = rsqrtf(var + LN_EPS);
        }
    }
    __syncthreads();
    // epilogue: affine (LN folded) + silu + bf16 store
    float sv[4], cv[4];
#pragma unroll
    for (int ni = 0; ni < 4; ++ni) {
        int c = wid * 64 + ni * 16 + (lane & 15);
        sv[ni] = svec[c];
        cv[ni] = c0[c];
    }
#pragma unroll
    for (int mi = 0; mi < 4; ++mi)
#pragma unroll
        for (int q = 0; q < 4; ++q) {
            int rl = mi * 16 + (lane >> 4) * 4 + q;
            float mu_ = muS[rl], rs_ = rsS[rl];
            size_t ro = (size_t)(r0 + rl) * HD;
#pragma unroll
            for (int ni = 0; ni < 4; ++ni) {
                float pre = rs_ * (acc[mi][ni][q] - mu_ * sv[ni]) + cv[ni];
                feat[ro + wid * 64 + ni * 16 + (lane & 15)] = f2b(silu_f(pre));
            }
        }
}

// ---------------- per-fragment feature sums (no atomics) -------------------
__global__ __launch_bounds__(64) void k_ssum(
    const unsigned short* __restrict__ feat, const int* __restrict__ order,
    const int* __restrict__ offs, const int* __restrict__ cnt,
    float* __restrict__ ssum) {
    int f = blockIdx.x;
    int lane = threadIdx.x;
    int base = offs[f], n = cnt[f];
    float4 acc = {0.f, 0.f, 0.f, 0.f};
    for (int a0 = 0; a0 < n; a0 += 64) {
        int idx = 0;
        if (a0 + lane < n) idx = order[base + a0 + lane];
        int m = n - a0; if (m > 64) m = 64;
        for (int j = 0; j < m; ++j) {
            int i = __shfl(idx, j, 64);
            ushort4 u = *(const ushort4*)(feat + (size_t)i * HD + lane * 4);
            acc.x += b2f(u.x); acc.y += b2f(u.y);
            acc.z += b2f(u.z); acc.w += b2f(u.w);
        }
    }
    *(float4*)(ssum + (size_t)f * HD + lane * 4) = acc;
}

// ---------------- fragment pass: coefs + normalized-row accumulation -------
__global__ __launch_bounds__(256) void k_frag(
    const float* __restrict__ ssum, const int* __restrict__ cnt,
    const float* __restrict__ vsum, const float* __restrict__ vfsum,
    float* __restrict__ fragcoef, float* __restrict__ vsign,
    double* __restrict__ dbl) {
    int gwave = (blockIdx.x * blockDim.x + threadIdx.x) >> 6;
    int lane = threadIdx.x & 63;
    int nw = (gridDim.x * blockDim.x) >> 6;

    double la0 = 0, la1 = 0, la2 = 0, la3 = 0;
    double lv = 0, ltr = 0, lvc = 0;

    for (int f = gwave; f < NF; f += nw) {
        float4 v = ((const float4*)(ssum + (size_t)f * HD))[lane];
        int c = cnt[f];
        float inv_all = 1.f / fmaxf((float)c, 1.f);
        float m0 = v.x * inv_all, m1 = v.y * inv_all, m2 = v.z * inv_all, m3 = v.w * inv_all;
        float ssq = wredsum(m0 * m0 + m1 * m1 + m2 * m2 + m3 * m3);
        float vfr = vsum[f] * inv_all;
        float nrm2 = ssq + vfr * vfr;
        float inv = 1.f / fmaxf(sqrtf(nrm2), NEPS);
        la0 += (double)(m0 * inv);
        la1 += (double)(m1 * inv);
        la2 += (double)(m2 * inv);
        la3 += (double)(m3 * inv);
        if (lane == 0) {
            lv += (double)(vfr * inv);
            ltr += (double)(nrm2 * inv * inv);
            if (c >= MINFRAG) {
                fragcoef[f] = 1.f / ((float)c * fmaxf(sqrtf(ssq), NEPS));
                float ms = vfsum[f] / (float)c;
                vsign[f] = ms / fmaxf(fabsf(ms), NEPS);
                lvc += (double)c;
            } else {
                fragcoef[f] = 0.f;
                vsign[f] = 0.f;
            }
        }
    }
    atomicAdd(&dbl[4 * lane + 0], la0);
    atomicAdd(&dbl[4 * lane + 1], la1);
    atomicAdd(&dbl[4 * lane + 2], la2);
    atomicAdd(&dbl[4 * lane + 3], la3);
    if (lane == 0) {
        atomicAdd(&dbl[256], lv);
        atomicAdd(&dbl[IDX_TRACE], ltr);
        atomicAdd(&dbl[IDX_VCNT], lvc);
    }
}

// ---------------- deviation pass (sorted order for ssum locality) ----------
__global__ __launch_bounds__(256) void k_dev(
    const unsigned short* __restrict__ feat, const float* __restrict__ ssum,
    const int* __restrict__ order, const int* __restrict__ fid,
    const int* __restrict__ cnt, const float* __restrict__ fragcoef,
    const float* __restrict__ vsign, const float* __restrict__ vmag,
    const float* __restrict__ w0p, double* __restrict__ dbl) {
    int gwave = (blockIdx.x * blockDim.x + threadIdx.x) >> 6;
    int lane = threadIdx.x & 63;
    int nw = (gridDim.x * blockDim.x) >> 6;
    float w0 = w0p[0];
    double accS = 0, accV = 0;
    for (int pos = gwave; pos < NA; pos += nw) {
        int i = order[pos];
        int f = fid[i];
        if (cnt[f] < MINFRAG) continue;
        ushort4 u = ((const ushort4*)(feat + (size_t)i * HD))[lane];
        float f0 = b2f(u.x), f1 = b2f(u.y), f2 = b2f(u.z), f3 = b2f(u.w);
        float4 ms = ((const float4*)(ssum + (size_t)f * HD))[lane];
        float dot = f0 * ms.x + f1 * ms.y + f2 * ms.z + f3 * ms.w;
        float nf = f0 * f0 + f1 * f1 + f2 * f2 + f3 * f3;
        dot = wredsum(dot);
        nf = wredsum(nf);
        if (lane == 0) {
            float sim = dot * fragcoef[f] / fmaxf(sqrtf(nf), NEPS);
            accS += (double)(1.f - sim);
            float vf = silu_f(vmag[i] * w0);
            float nv = vf / fmaxf(fabsf(vf), NEPS);
            accV += (double)(1.f - nv * vsign[f]);
        }
    }
    if (lane == 0) {
        atomicAdd(&dbl[IDX_DEVS], accS);
        atomicAdd(&dbl[IDX_DEVV], accV);
    }
}

// ---------------- final combine ----------------
__global__ __launch_bounds__(64) void k_final(const double* __restrict__ dbl,
                                              float* __restrict__ out) {
    if (threadIdx.x == 0 && blockIdx.x == 0) {
        double s2 = 0;
        for (int d = 0; d < 257; ++d) s2 += dbl[d] * dbl[d];
        double off = s2 - dbl[IDX_TRACE];
        double inter = off / ((double)NF * NF - NF + 1e-6);
        double vc = fmax(dbl[IDX_VCNT], 1.0);
        double total = dbl[IDX_DEVS] / vc + dbl[IDX_DEVV] / vc + 0.2 * inter;
        out[0] = (float)(0.03 * 0.05 * total);
    }
}

extern "C" void kernel_launch(void* const* d_in, const int* in_sizes, int n_in,
                              void* d_out, int out_size, void* d_ws, size_t ws_size,
                              hipStream_t stream) {
    const float* scalar_short = (const float*)d_in[0];
    const float* vector_short = (const float*)d_in[2];
    const int* fragment_ids = (const int*)d_in[4];
    const float* ln_gamma = (const float*)d_in[5];
    const float* ln_beta = (const float*)d_in[6];
    const float* W1 = (const float*)d_in[7];
    const float* b1 = (const float*)d_in[8];
    const float* Wv = (const float*)d_in[9];
    float* out = (float*)d_out;

    char* ws = (char*)d_ws;
    int* cnt = (int*)(ws + OFF_CNT);
    float* vsum = (float*)(ws + OFF_VSUM);
    float* vfsum = (float*)(ws + OFF_VFSUM);
    int* fill = (int*)(ws + OFF_FILL);
    double* dbl = (double*)(ws + OFF_DBL);
    int* offs = (int*)(ws + OFF_OFFS);
    float* fragcoef = (float*)(ws + OFF_FRAGC);
    float* vsign = (float*)(ws + OFF_VSIGN);
    float* svec = (float*)(ws + OFF_SVEC);
    float* c0 = (float*)(ws + OFF_C0);
    float* w0 = (float*)(ws + OFF_W0);
    float* vmag = (float*)(ws + OFF_VMAG);
    int* order = (int*)(ws + OFF_ORDER);
    unsigned short* Gbf = (unsigned short*)(ws + OFF_GBF);
    float* ssum = (float*)(ws + OFF_SSUM);
    unsigned short* feat = (unsigned short*)(ws + OFF_FEAT);

    hipMemsetAsync(ws, 0, ZERO_BYTES, stream);
    k_prep<<<HD + 1, 256, 0, stream>>>(W1, ln_gamma, ln_beta, b1, Wv, Gbf, svec, c0, w0);
    k_stats<<<2048, 256, 0, stream>>>(vector_short, fragment_ids, w0, vmag, cnt, vsum, vfsum);
    k_scan<<<1, 256, 0, stream>>>(cnt, offs);
    k_scatter<<<NA / 256, 256, 0, stream>>>(fragment_ids, offs, fill, order);
    k_gemm<<<NA / 64, 256, 0, stream>>>(scalar_short, Gbf, svec, c0, feat);
    k_ssum<<<NF, 64, 0, stream>>>(feat, order, offs, cnt, ssum);
    k_frag<<<64, 256, 0, stream>>>(ssum, cnt, vsum, vfsum, fragcoef, vsign, dbl);
    k_dev<<<2048, 256, 0, stream>>>(feat, ssum, order, fragment_ids, cnt, fragcoef,
                                    vsign, vmag, w0, dbl);
    k_final<<<1, 64, 0, stream>>>(dbl, out);
}

// Round 3
// 256.567 us; speedup vs baseline: 2.4975x; 1.8475x over previous
//
#include <hip/hip_runtime.h>
#include <hip/hip_bf16.h>
#include <stdint.h>

#define NA 131072
#define HD 256
#define NF 4096
#define MINFRAG 3
#define LN_EPS 1e-5f
#define NEPS 1e-12f

// ---- workspace layout (bytes) ----
// zeroed region first
#define OFF_CNT    0ull          // NF i32
#define OFF_VSUM   16384ull      // NF f32 (sum vec_mag)
#define OFF_VFSUM  32768ull      // NF f32 (sum silu(vm*w0))
#define OFF_NVSUM  49152ull      // NF f32 (sum normalize(vf))
#define OFF_FILL   65536ull      // NF i32
#define OFF_DBL    81920ull      // 261 doubles
#define ZERO_BYTES 84008ull
// non-zeroed
#define OFF_OFFS   86016ull      // NF i32
#define OFF_SVEC   102400ull     // HD f32
#define OFF_C0     103424ull     // HD f32
#define OFF_W0     104448ull     // 1 f32
#define OFF_RNORM  131072ull     // NA f32
#define OFF_ORDER  655360ull     // NA i32
#define OFF_GBF    1179648ull    // HD*HD bf16
#define OFF_SSUM   1310720ull    // NF*HD f32
#define OFF_NSUM   5505024ull    // NF*HD f32
#define OFF_FEAT   9699328ull    // NA*HD bf16
// total: 76,808,192 bytes

#define IDX_TRACE 257
#define IDX_DEVS  258
#define IDX_DEVV  259
#define IDX_VCNT  260

typedef __attribute__((ext_vector_type(8))) short short8;
typedef __attribute__((ext_vector_type(4))) float f32x4;
union F4S8 { float4 f; short8 s; };
union BFU { __hip_bfloat16 b; unsigned short u; };

__device__ __forceinline__ unsigned short f2b(float x) {
    BFU t; t.b = __float2bfloat16(x); return t.u;
}
__device__ __forceinline__ float b2f(unsigned short u) {
    return __uint_as_float(((uint32_t)u) << 16);
}
__device__ __forceinline__ float wredsum(float v) {
#pragma unroll
    for (int m = 32; m; m >>= 1) v += __shfl_xor(v, m, 64);
    return v;
}
__device__ __forceinline__ float silu_f(float x) { return x / (1.f + expf(-x)); }

// ---------------- prep ----------------
__global__ __launch_bounds__(256) void k_prep(
    const float* __restrict__ W1, const float* __restrict__ gamma,
    const float* __restrict__ beta, const float* __restrict__ b1,
    const float* __restrict__ Wv,
    unsigned short* __restrict__ Gbf, float* __restrict__ svec,
    float* __restrict__ c0, float* __restrict__ w0) {
    __shared__ float red[8];
    int o = blockIdx.x;
    int t = threadIdx.x;  // == h
    if (o < HD) {
        float w = W1[(size_t)o * HD + t];
        unsigned short gb = f2b(w * gamma[t]);
        Gbf[(size_t)o * HD + t] = gb;
        float sp = b2f(gb);
        float cp = w * beta[t];
#pragma unroll
        for (int m = 32; m; m >>= 1) { sp += __shfl_xor(sp, m, 64); cp += __shfl_xor(cp, m, 64); }
        int wv = t >> 6;
        if ((t & 63) == 0) { red[wv] = sp; red[4 + wv] = cp; }
        __syncthreads();
        if (t == 0) {
            svec[o] = red[0] + red[1] + red[2] + red[3];
            c0[o]   = red[4] + red[5] + red[6] + red[7] + b1[o];
        }
    } else {
        float v = Wv[t];
#pragma unroll
        for (int m = 32; m; m >>= 1) v += __shfl_xor(v, m, 64);
        int wv = t >> 6;
        if ((t & 63) == 0) red[wv] = v;
        __syncthreads();
        if (t == 0) w0[0] = red[0] + red[1] + red[2] + red[3];
    }
}

// ---------------- stats: vec branch fully folded to per-fragment sums ------
__global__ __launch_bounds__(256) void k_stats(
    const float* __restrict__ vs, const int* __restrict__ fid,
    const float* __restrict__ w0p,
    int* __restrict__ cnt, float* __restrict__ vsum,
    float* __restrict__ vfsum, float* __restrict__ nvsum) {
    int gwave = (blockIdx.x * blockDim.x + threadIdx.x) >> 6;
    int lane = threadIdx.x & 63;
    int nw = (gridDim.x * blockDim.x) >> 6;
    float w0 = w0p[0];
    for (int i = gwave; i < NA; i += nw) {
        const float* base = vs + (size_t)i * 3 * HD;
        float4 v0 = ((const float4*)(base))[lane];
        float4 v1 = ((const float4*)(base + HD))[lane];
        float4 v2 = ((const float4*)(base + 2 * HD))[lane];
        float q0 = v0.x * v0.x + v0.y * v0.y + v0.z * v0.z + v0.w * v0.w;
        float q1 = v1.x * v1.x + v1.y * v1.y + v1.z * v1.z + v1.w * v1.w;
        float q2 = v2.x * v2.x + v2.y * v2.y + v2.z * v2.z + v2.w * v2.w;
#pragma unroll
        for (int m = 32; m; m >>= 1) {   // three independent chains, interleaved
            q0 += __shfl_xor(q0, m, 64);
            q1 += __shfl_xor(q1, m, 64);
            q2 += __shfl_xor(q2, m, 64);
        }
        if (lane == 0) {
            float vm = (sqrtf(q0) + sqrtf(q1) + sqrtf(q2)) * (1.f / 3.f);
            float vf = silu_f(vm * w0);
            float nv = vf / fmaxf(fabsf(vf), NEPS);
            int f = fid[i];
            atomicAdd(&cnt[f], 1);
            atomicAdd(&vsum[f], vm);
            atomicAdd(&vfsum[f], vf);
            atomicAdd(&nvsum[f], nv);
        }
    }
}

// ---------------- scan ----------------
__global__ __launch_bounds__(256) void k_scan(const int* __restrict__ cnt,
                                              int* __restrict__ offs) {
    __shared__ int wsum[4];
    int t = threadIdx.x;
    int base = t * 16;
    int c[16];
    int tot = 0;
#pragma unroll
    for (int j = 0; j < 16; ++j) { c[j] = cnt[base + j]; tot += c[j]; }
    int lane = t & 63, w = t >> 6;
    int v = tot;
#pragma unroll
    for (int d = 1; d < 64; d <<= 1) {
        int o = __shfl_up(v, d, 64);
        if (lane >= d) v += o;
    }
    if (lane == 63) wsum[w] = v;
    __syncthreads();
    int wbase = 0;
    for (int i = 0; i < w; ++i) wbase += wsum[i];
    int run = wbase + v - tot;
#pragma unroll
    for (int j = 0; j < 16; ++j) { offs[base + j] = run; run += c[j]; }
}

// ---------------- scatter ----------------
__global__ __launch_bounds__(256) void k_scatter(
    const int* __restrict__ fid, const int* __restrict__ offs,
    int* __restrict__ fill, int* __restrict__ order) {
    int i = blockIdx.x * blockDim.x + threadIdx.x;
    if (i < NA) {
        int f = fid[i];
        int p = atomicAdd(&fill[f], 1);
        order[offs[f] + p] = i;
    }
}

// ---------------- GEMM + LN + silu + per-row rnorm ----------------
__global__ __launch_bounds__(256) void k_gemm(
    const float* __restrict__ A, const unsigned short* __restrict__ Gbf,
    const float* __restrict__ svec, const float* __restrict__ c0,
    unsigned short* __restrict__ feat, float* __restrict__ rnorm) {
    __shared__ float4 As16[64 * 8];
    __shared__ float4 Bs16[256 * 8];
    __shared__ float muS[64], rsS[64];
    __shared__ float sqL[64][4];

    int tid = threadIdx.x;
    int lane = tid & 63, wid = tid >> 6;
    int r0 = blockIdx.x * 64;
    int rowT = tid >> 4;
    int c4 = tid & 15;

    f32x4 acc[4][4] = {};
    float s1p[4] = {0, 0, 0, 0}, s2p[4] = {0, 0, 0, 0};

    for (int k0 = 0; k0 < HD; k0 += 64) {
#pragma unroll
        for (int p = 0; p < 4; ++p) {
            int row = 16 * p + rowT;
            float4 v = *(const float4*)(A + (size_t)(r0 + row) * HD + k0 + c4 * 4);
            s1p[p] += v.x + v.y + v.z + v.w;
            s2p[p] += v.x * v.x + v.y * v.y + v.z * v.z + v.w * v.w;
            ushort4 pk;
            pk.x = f2b(v.x); pk.y = f2b(v.y); pk.z = f2b(v.z); pk.w = f2b(v.w);
            int slot = row * 8 + ((c4 >> 1) ^ (row & 7));
            ((ushort4*)&As16[slot])[c4 & 1] = pk;
        }
#pragma unroll
        for (int p = 0; p < 8; ++p) {
            int u = p * 256 + tid;
            int n = u >> 3, cc = u & 7;
            float4 g = *(const float4*)(Gbf + (size_t)n * HD + k0 + cc * 8);
            Bs16[n * 8 + (cc ^ (n & 7))] = g;
        }
        __syncthreads();
#pragma unroll
        for (int kk = 0; kk < 2; ++kk) {
            int uo = kk * 4 + (lane >> 4);
            short8 a[4], b[4];
#pragma unroll
            for (int mi = 0; mi < 4; ++mi) {
                int r = mi * 16 + (lane & 15);
                F4S8 t_; t_.f = As16[r * 8 + (uo ^ (r & 7))];
                a[mi] = t_.s;
            }
#pragma unroll
            for (int ni = 0; ni < 4; ++ni) {
                int n = wid * 64 + ni * 16 + (lane & 15);
                F4S8 t_; t_.f = Bs16[n * 8 + (uo ^ (n & 7))];
                b[ni] = t_.s;
            }
#pragma unroll
            for (int mi = 0; mi < 4; ++mi)
#pragma unroll
                for (int ni = 0; ni < 4; ++ni)
                    acc[mi][ni] = __builtin_amdgcn_mfma_f32_16x16x32_bf16(
                        a[mi], b[ni], acc[mi][ni], 0, 0, 0);
        }
        __syncthreads();
    }
#pragma unroll
    for (int p = 0; p < 4; ++p) {
        float s1 = s1p[p], s2 = s2p[p];
#pragma unroll
        for (int m = 1; m < 16; m <<= 1) {
            s1 += __shfl_xor(s1, m, 64);
            s2 += __shfl_xor(s2, m, 64);
        }
        if (c4 == 0) {
            int row = 16 * p + rowT;
            float mu_ = s1 * (1.f / HD);
            float var = s2 * (1.f / HD) - mu_ * mu_;
            muS[row] = mu_;
            rsS[row] = rsqrtf(var + LN_EPS);
        }
    }
    __syncthreads();
    float sv[4], cv[4];
#pragma unroll
    for (int ni = 0; ni < 4; ++ni) {
        int c = wid * 64 + ni * 16 + (lane & 15);
        sv[ni] = svec[c];
        cv[ni] = c0[c];
    }
    float sq[4][4];
#pragma unroll
    for (int mi = 0; mi < 4; ++mi)
#pragma unroll
        for (int q = 0; q < 4; ++q) {
            int rl = mi * 16 + (lane >> 4) * 4 + q;
            float mu_ = muS[rl], rs_ = rsS[rl];
            size_t ro = (size_t)(r0 + rl) * HD;
            float sqa = 0.f;
#pragma unroll
            for (int ni = 0; ni < 4; ++ni) {
                float pre = rs_ * (acc[mi][ni][q] - mu_ * sv[ni]) + cv[ni];
                unsigned short us = f2b(silu_f(pre));
                feat[ro + wid * 64 + ni * 16 + (lane & 15)] = us;
                float fr = b2f(us);
                sqa += fr * fr;
            }
            sq[mi][q] = sqa;
        }
    // per-row squared-norm: reduce 16 lanes, then 4 waves via LDS
#pragma unroll
    for (int mi = 0; mi < 4; ++mi)
#pragma unroll
        for (int q = 0; q < 4; ++q) {
            float s_ = sq[mi][q];
            s_ += __shfl_xor(s_, 1, 64);
            s_ += __shfl_xor(s_, 2, 64);
            s_ += __shfl_xor(s_, 4, 64);
            s_ += __shfl_xor(s_, 8, 64);
            if ((lane & 15) == 0) sqL[mi * 16 + (lane >> 4) * 4 + q][wid] = s_;
        }
    __syncthreads();
    if (tid < 64) {
        float t = sqL[tid][0] + sqL[tid][1] + sqL[tid][2] + sqL[tid][3];
        rnorm[r0 + tid] = 1.f / fmaxf(sqrtf(t), NEPS);
    }
}

// ---------------- per-fragment sums: ssum + normalized nsum ---------------
__global__ __launch_bounds__(256) void k_ssum(
    const unsigned short* __restrict__ feat, const float* __restrict__ rnorm,
    const int* __restrict__ order, const int* __restrict__ offs,
    const int* __restrict__ cnt, float* __restrict__ ssum,
    float* __restrict__ nsum) {
    int wid = threadIdx.x >> 6, lane = threadIdx.x & 63;
    int f = blockIdx.x * 4 + wid;
    int base = offs[f], n = cnt[f];
    float4 as = {0.f, 0.f, 0.f, 0.f};
    float4 an = {0.f, 0.f, 0.f, 0.f};
    for (int a0 = 0; a0 < n; a0 += 64) {
        int idx = 0;
        float rn = 0.f;
        if (a0 + lane < n) {
            idx = order[base + a0 + lane];
            rn = rnorm[idx];
        }
        int m = n - a0; if (m > 64) m = 64;
        for (int j = 0; j < m; ++j) {
            int i = __shfl(idx, j, 64);
            float r = __shfl(rn, j, 64);
            ushort4 u = *(const ushort4*)(feat + (size_t)i * HD + lane * 4);
            float f0 = b2f(u.x), f1 = b2f(u.y), f2 = b2f(u.z), f3 = b2f(u.w);
            as.x += f0; as.y += f1; as.z += f2; as.w += f3;
            an.x = fmaf(f0, r, an.x); an.y = fmaf(f1, r, an.y);
            an.z = fmaf(f2, r, an.z); an.w = fmaf(f3, r, an.w);
        }
    }
    *(float4*)(ssum + (size_t)f * HD + lane * 4) = as;
    *(float4*)(nsum + (size_t)f * HD + lane * 4) = an;
}

// ---------------- fragment pass: devS, devV, combined accumulation --------
__global__ __launch_bounds__(256) void k_frag(
    const float* __restrict__ ssum, const float* __restrict__ nsum,
    const int* __restrict__ cnt, const float* __restrict__ vsum,
    const float* __restrict__ vfsum, const float* __restrict__ nvsum,
    double* __restrict__ dbl) {
    int gwave = (blockIdx.x * blockDim.x + threadIdx.x) >> 6;
    int lane = threadIdx.x & 63;
    int nw = (gridDim.x * blockDim.x) >> 6;

    double la0 = 0, la1 = 0, la2 = 0, la3 = 0;
    double lv = 0, ltr = 0, lvc = 0, ldS = 0, ldV = 0;

    for (int f = gwave; f < NF; f += nw) {
        float4 s = ((const float4*)(ssum + (size_t)f * HD))[lane];
        float4 nn = ((const float4*)(nsum + (size_t)f * HD))[lane];
        int c = cnt[f];
        float ssq = s.x * s.x + s.y * s.y + s.z * s.z + s.w * s.w;
        float dsn = nn.x * s.x + nn.y * s.y + nn.z * s.z + nn.w * s.w;
#pragma unroll
        for (int m = 32; m; m >>= 1) {
            ssq += __shfl_xor(ssq, m, 64);
            dsn += __shfl_xor(dsn, m, 64);
        }
        float inv_all = 1.f / fmaxf((float)c, 1.f);
        float m0 = s.x * inv_all, m1 = s.y * inv_all, m2 = s.z * inv_all, m3 = s.w * inv_all;
        float ssq_mean = ssq * inv_all * inv_all;
        float vfr = vsum[f] * inv_all;
        float nrm2 = ssq_mean + vfr * vfr;
        float inv = 1.f / fmaxf(sqrtf(nrm2), NEPS);
        la0 += (double)(m0 * inv);
        la1 += (double)(m1 * inv);
        la2 += (double)(m2 * inv);
        la3 += (double)(m3 * inv);
        if (lane == 0) {
            lv += (double)(vfr * inv);
            ltr += (double)(nrm2 * inv * inv);
            if (c >= MINFRAG) {
                lvc += (double)c;
                float denom = fmaxf(sqrtf(ssq), NEPS);
                ldS += (double)c - (double)(dsn / denom);
                float vfm = vfsum[f] * inv_all;
                float vsgn = vfm / fmaxf(fabsf(vfm), NEPS);
                ldV += (double)c - (double)(vsgn * nvsum[f]);
            }
        }
    }
    atomicAdd(&dbl[4 * lane + 0], la0);
    atomicAdd(&dbl[4 * lane + 1], la1);
    atomicAdd(&dbl[4 * lane + 2], la2);
    atomicAdd(&dbl[4 * lane + 3], la3);
    if (lane == 0) {
        atomicAdd(&dbl[256], lv);
        atomicAdd(&dbl[IDX_TRACE], ltr);
        atomicAdd(&dbl[IDX_VCNT], lvc);
        atomicAdd(&dbl[IDX_DEVS], ldS);
        atomicAdd(&dbl[IDX_DEVV], ldV);
    }
}

// ---------------- final combine ----------------
__global__ __launch_bounds__(64) void k_final(const double* __restrict__ dbl,
                                              float* __restrict__ out) {
    if (threadIdx.x == 0 && blockIdx.x == 0) {
        double s2 = 0;
        for (int d = 0; d < 257; ++d) s2 += dbl[d] * dbl[d];
        double off = s2 - dbl[IDX_TRACE];
        double inter = off / ((double)NF * NF - NF + 1e-6);
        double vc = fmax(dbl[IDX_VCNT], 1.0);
        double total = dbl[IDX_DEVS] / vc + dbl[IDX_DEVV] / vc + 0.2 * inter;
        out[0] = (float)(0.03 * 0.05 * total);
    }
}

extern "C" void kernel_launch(void* const* d_in, const int* in_sizes, int n_in,
                              void* d_out, int out_size, void* d_ws, size_t ws_size,
                              hipStream_t stream) {
    const float* scalar_short = (const float*)d_in[0];
    const float* vector_short = (const float*)d_in[2];
    const int* fragment_ids = (const int*)d_in[4];
    const float* ln_gamma = (const float*)d_in[5];
    const float* ln_beta = (const float*)d_in[6];
    const float* W1 = (const float*)d_in[7];
    const float* b1 = (const float*)d_in[8];
    const float* Wv = (const float*)d_in[9];
    float* out = (float*)d_out;

    char* ws = (char*)d_ws;
    int* cnt = (int*)(ws + OFF_CNT);
    float* vsum = (float*)(ws + OFF_VSUM);
    float* vfsum = (float*)(ws + OFF_VFSUM);
    float* nvsum = (float*)(ws + OFF_NVSUM);
    int* fill = (int*)(ws + OFF_FILL);
    double* dbl = (double*)(ws + OFF_DBL);
    int* offs = (int*)(ws + OFF_OFFS);
    float* svec = (float*)(ws + OFF_SVEC);
    float* c0 = (float*)(ws + OFF_C0);
    float* w0 = (float*)(ws + OFF_W0);
    float* rnorm = (float*)(ws + OFF_RNORM);
    int* order = (int*)(ws + OFF_ORDER);
    unsigned short* Gbf = (unsigned short*)(ws + OFF_GBF);
    float* ssum = (float*)(ws + OFF_SSUM);
    float* nsum = (float*)(ws + OFF_NSUM);
    unsigned short* feat = (unsigned short*)(ws + OFF_FEAT);

    hipMemsetAsync(ws, 0, ZERO_BYTES, stream);
    k_prep<<<HD + 1, 256, 0, stream>>>(W1, ln_gamma, ln_beta, b1, Wv, Gbf, svec, c0, w0);
    k_stats<<<2048, 256, 0, stream>>>(vector_short, fragment_ids, w0, cnt, vsum, vfsum, nvsum);
    k_scan<<<1, 256, 0, stream>>>(cnt, offs);
    k_scatter<<<NA / 256, 256, 0, stream>>>(fragment_ids, offs, fill, order);
    k_gemm<<<NA / 64, 256, 0, stream>>>(scalar_short, Gbf, svec, c0, feat, rnorm);
    k_ssum<<<NF / 4, 256, 0, stream>>>(feat, rnorm, order, offs, cnt, ssum, nsum);
    k_frag<<<64, 256, 0, stream>>>(ssum, nsum, cnt, vsum, vfsum, nvsum, dbl);
    k_final<<<1, 64, 0, stream>>>(dbl, out);
}

// Round 4
// 252.664 us; speedup vs baseline: 2.5361x; 1.0154x over previous
//
#include <hip/hip_runtime.h>
#include <hip/hip_bf16.h>
#include <stdint.h>

#define NA 131072
#define HD 256
#define NF 4096
#define MINFRAG 3
#define LN_EPS 1e-5f
#define NEPS 1e-12f

// ---- workspace layout (bytes) ----
// zeroed region
#define OFF_CNT    0ull          // NF i32
#define OFF_VSUM   16384ull      // NF f32
#define OFF_VFSUM  32768ull      // NF f32
#define OFF_NVSUM  49152ull      // NF f32
#define OFF_FILL   65536ull      // NF i32
#define OFF_DBL    81920ull      // 261 doubles (ends 84008)
#define OFF_SSUM   86016ull      // NF*HD f32 = 4194304
#define OFF_NSUM   4280320ull    // NF*HD f32 = 4194304
#define ZERO_BYTES 8474624ull
// non-zeroed
#define OFF_OFFS   8474624ull    // NF i32
#define OFF_SVEC   8491008ull    // HD f32
#define OFF_C0     8492032ull    // HD f32
#define OFF_W0     8493056ull    // 1 f32
#define OFF_GBF    8493568ull    // HD*HD bf16 = 131072
#define OFF_ORDER  8624640ull    // NA i32 = 524288
// total: 9,148,928 bytes

#define IDX_TRACE 257
#define IDX_DEVS  258
#define IDX_DEVV  259
#define IDX_VCNT  260

typedef __attribute__((ext_vector_type(8))) short short8;
typedef __attribute__((ext_vector_type(4))) float f32x4;
union F4S8 { float4 f; short8 s; };
union BFU { __hip_bfloat16 b; unsigned short u; };

__device__ __forceinline__ unsigned short f2b(float x) {
    BFU t; t.b = __float2bfloat16(x); return t.u;
}
__device__ __forceinline__ float b2f(unsigned short u) {
    return __uint_as_float(((uint32_t)u) << 16);
}
__device__ __forceinline__ float silu_f(float x) { return x / (1.f + expf(-x)); }

// ---------------- prep ----------------
__global__ __launch_bounds__(256) void k_prep(
    const float* __restrict__ W1, const float* __restrict__ gamma,
    const float* __restrict__ beta, const float* __restrict__ b1,
    const float* __restrict__ Wv,
    unsigned short* __restrict__ Gbf, float* __restrict__ svec,
    float* __restrict__ c0, float* __restrict__ w0) {
    __shared__ float red[8];
    int o = blockIdx.x;
    int t = threadIdx.x;  // == h
    if (o < HD) {
        float w = W1[(size_t)o * HD + t];
        unsigned short gb = f2b(w * gamma[t]);
        Gbf[(size_t)o * HD + t] = gb;
        float sp = b2f(gb);
        float cp = w * beta[t];
#pragma unroll
        for (int m = 32; m; m >>= 1) { sp += __shfl_xor(sp, m, 64); cp += __shfl_xor(cp, m, 64); }
        int wv = t >> 6;
        if ((t & 63) == 0) { red[wv] = sp; red[4 + wv] = cp; }
        __syncthreads();
        if (t == 0) {
            svec[o] = red[0] + red[1] + red[2] + red[3];
            c0[o]   = red[4] + red[5] + red[6] + red[7] + b1[o];
        }
    } else {
        float v = Wv[t];
#pragma unroll
        for (int m = 32; m; m >>= 1) v += __shfl_xor(v, m, 64);
        int wv = t >> 6;
        if ((t & 63) == 0) red[wv] = v;
        __syncthreads();
        if (t == 0) w0[0] = red[0] + red[1] + red[2] + red[3];
    }
}

// ---------------- stats: vec branch folded to per-fragment sums ------------
__global__ __launch_bounds__(256) void k_stats(
    const float* __restrict__ vs, const int* __restrict__ fid,
    const float* __restrict__ w0p,
    int* __restrict__ cnt, float* __restrict__ vsum,
    float* __restrict__ vfsum, float* __restrict__ nvsum) {
    int gwave = (blockIdx.x * blockDim.x + threadIdx.x) >> 6;
    int lane = threadIdx.x & 63;
    int nw = (gridDim.x * blockDim.x) >> 6;
    float w0 = w0p[0];
    for (int i = gwave; i < NA; i += nw) {
        const float* base = vs + (size_t)i * 3 * HD;
        float4 v0 = ((const float4*)(base))[lane];
        float4 v1 = ((const float4*)(base + HD))[lane];
        float4 v2 = ((const float4*)(base + 2 * HD))[lane];
        float q0 = v0.x * v0.x + v0.y * v0.y + v0.z * v0.z + v0.w * v0.w;
        float q1 = v1.x * v1.x + v1.y * v1.y + v1.z * v1.z + v1.w * v1.w;
        float q2 = v2.x * v2.x + v2.y * v2.y + v2.z * v2.z + v2.w * v2.w;
#pragma unroll
        for (int m = 32; m; m >>= 1) {
            q0 += __shfl_xor(q0, m, 64);
            q1 += __shfl_xor(q1, m, 64);
            q2 += __shfl_xor(q2, m, 64);
        }
        if (lane == 0) {
            float vm = (sqrtf(q0) + sqrtf(q1) + sqrtf(q2)) * (1.f / 3.f);
            float vf = silu_f(vm * w0);
            float nv = vf / fmaxf(fabsf(vf), NEPS);
            int f = fid[i];
            atomicAdd(&cnt[f], 1);
            atomicAdd(&vsum[f], vm);
            atomicAdd(&vfsum[f], vf);
            atomicAdd(&nvsum[f], nv);
        }
    }
}

// ---------------- scan ----------------
__global__ __launch_bounds__(256) void k_scan(const int* __restrict__ cnt,
                                              int* __restrict__ offs) {
    __shared__ int wsum[4];
    int t = threadIdx.x;
    int base = t * 16;
    int c[16];
    int tot = 0;
#pragma unroll
    for (int j = 0; j < 16; ++j) { c[j] = cnt[base + j]; tot += c[j]; }
    int lane = t & 63, w = t >> 6;
    int v = tot;
#pragma unroll
    for (int d = 1; d < 64; d <<= 1) {
        int o = __shfl_up(v, d, 64);
        if (lane >= d) v += o;
    }
    if (lane == 63) wsum[w] = v;
    __syncthreads();
    int wbase = 0;
    for (int i = 0; i < w; ++i) wbase += wsum[i];
    int run = wbase + v - tot;
#pragma unroll
    for (int j = 0; j < 16; ++j) { offs[base + j] = run; run += c[j]; }
}

// ---------------- scatter ----------------
__global__ __launch_bounds__(256) void k_scatter(
    const int* __restrict__ fid, const int* __restrict__ offs,
    int* __restrict__ fill, int* __restrict__ order) {
    int i = blockIdx.x * blockDim.x + threadIdx.x;
    if (i < NA) {
        int f = fid[i];
        int p = atomicAdd(&fill[f], 1);
        order[offs[f] + p] = i;
    }
}

// ---- GEMM (sorted rows) + LN + silu + fused fragment ssum/nsum ----
__global__ __launch_bounds__(256) void k_gemm(
    const float* __restrict__ A, const unsigned short* __restrict__ Gbf,
    const float* __restrict__ svec, const float* __restrict__ c0,
    const int* __restrict__ order, const int* __restrict__ fid,
    const int* __restrict__ offs, const int* __restrict__ cnt,
    float* __restrict__ ssum, float* __restrict__ nsum) {
    __shared__ float4 As16[64 * 8];     // 8 KB
    __shared__ float4 Bs16[256 * 8];    // 32 KB; reused as bf16 feat[64][256]
    __shared__ float muS[64], rsS[64], rnS[64];
    __shared__ float sqL[64][4];
    __shared__ int fragS[64];

    int tid = threadIdx.x;
    int lane = tid & 63, wid = tid >> 6;
    int r0 = blockIdx.x * 64;
    int rowT = tid >> 4;   // 0..15
    int c4 = tid & 15;

    if (tid < 64) {
        int gi = order[r0 + tid];
        muS[tid] = __int_as_float(gi);   // temp stash of row ids
        fragS[tid] = fid[gi];
    }
    __syncthreads();
    int rid[4];
#pragma unroll
    for (int p = 0; p < 4; ++p) rid[p] = __float_as_int(muS[16 * p + rowT]);
    __syncthreads();

    f32x4 acc[4][4] = {};
    float s1p[4] = {0, 0, 0, 0}, s2p[4] = {0, 0, 0, 0};

    for (int k0 = 0; k0 < HD; k0 += 64) {
#pragma unroll
        for (int p = 0; p < 4; ++p) {
            int row = 16 * p + rowT;
            float4 v = *(const float4*)(A + (size_t)rid[p] * HD + k0 + c4 * 4);
            s1p[p] += v.x + v.y + v.z + v.w;
            s2p[p] += v.x * v.x + v.y * v.y + v.z * v.z + v.w * v.w;
            ushort4 pk;
            pk.x = f2b(v.x); pk.y = f2b(v.y); pk.z = f2b(v.z); pk.w = f2b(v.w);
            int slot = row * 8 + ((c4 >> 1) ^ (row & 7));
            ((ushort4*)&As16[slot])[c4 & 1] = pk;
        }
#pragma unroll
        for (int p = 0; p < 8; ++p) {
            int u = p * 256 + tid;
            int n = u >> 3, cc = u & 7;
            float4 g = *(const float4*)(Gbf + (size_t)n * HD + k0 + cc * 8);
            Bs16[n * 8 + (cc ^ (n & 7))] = g;
        }
        __syncthreads();
#pragma unroll
        for (int kk = 0; kk < 2; ++kk) {
            int uo = kk * 4 + (lane >> 4);
            short8 a[4], b[4];
#pragma unroll
            for (int mi = 0; mi < 4; ++mi) {
                int r = mi * 16 + (lane & 15);
                F4S8 t_; t_.f = As16[r * 8 + (uo ^ (r & 7))];
                a[mi] = t_.s;
            }
#pragma unroll
            for (int ni = 0; ni < 4; ++ni) {
                int n = wid * 64 + ni * 16 + (lane & 15);
                F4S8 t_; t_.f = Bs16[n * 8 + (uo ^ (n & 7))];
                b[ni] = t_.s;
            }
#pragma unroll
            for (int mi = 0; mi < 4; ++mi)
#pragma unroll
                for (int ni = 0; ni < 4; ++ni)
                    acc[mi][ni] = __builtin_amdgcn_mfma_f32_16x16x32_bf16(
                        a[mi], b[ni], acc[mi][ni], 0, 0, 0);
        }
        __syncthreads();
    }
    // LN row stats (muS was consumed as rowid stash before first staging sync)
#pragma unroll
    for (int p = 0; p < 4; ++p) {
        float s1 = s1p[p], s2 = s2p[p];
#pragma unroll
        for (int m = 1; m < 16; m <<= 1) {
            s1 += __shfl_xor(s1, m, 64);
            s2 += __shfl_xor(s2, m, 64);
        }
        if (c4 == 0) {
            int row = 16 * p + rowT;
            float mu_ = s1 * (1.f / HD);
            float var = s2 * (1.f / HD) - mu_ * mu_;
            muS[row] = mu_;
            rsS[row] = rsqrtf(var + LN_EPS);
        }
    }
    __syncthreads();
    float sv[4], cv[4];
#pragma unroll
    for (int ni = 0; ni < 4; ++ni) {
        int c = wid * 64 + ni * 16 + (lane & 15);
        sv[ni] = svec[c];
        cv[ni] = c0[c];
    }
    // feat -> LDS (bf16, xor-swizzled per row), per-row sq accumulation
    unsigned short* featS = (unsigned short*)Bs16;
    float sq[4][4];
#pragma unroll
    for (int mi = 0; mi < 4; ++mi)
#pragma unroll
        for (int q = 0; q < 4; ++q) {
            int rl = mi * 16 + (lane >> 4) * 4 + q;
            float mu_ = muS[rl], rs_ = rsS[rl];
            float sqa = 0.f;
#pragma unroll
            for (int ni = 0; ni < 4; ++ni) {
                int c = wid * 64 + ni * 16 + (lane & 15);
                float pre = rs_ * (acc[mi][ni][q] - mu_ * sv[ni]) + cv[ni];
                unsigned short us = f2b(silu_f(pre));
                featS[rl * 256 + (c ^ ((rl & 7) << 2))] = us;
                float fr = b2f(us);
                sqa += fr * fr;
            }
            sq[mi][q] = sqa;
        }
#pragma unroll
    for (int mi = 0; mi < 4; ++mi)
#pragma unroll
        for (int q = 0; q < 4; ++q) {
            float s_ = sq[mi][q];
            s_ += __shfl_xor(s_, 1, 64);
            s_ += __shfl_xor(s_, 2, 64);
            s_ += __shfl_xor(s_, 4, 64);
            s_ += __shfl_xor(s_, 8, 64);
            if ((lane & 15) == 0) sqL[mi * 16 + (lane >> 4) * 4 + q][wid] = s_;
        }
    __syncthreads();
    if (tid < 64) {
        float t = sqL[tid][0] + sqL[tid][1] + sqL[tid][2] + sqL[tid][3];
        rnS[tid] = 1.f / fmaxf(sqrtf(t), NEPS);
    }
    __syncthreads();
    // fragment-segment accumulation: one column per thread, scan 64 rows
    int cc = wid * 64 + lane;
    float sAcc = 0.f, nAcc = 0.f;
    int curF = fragS[0];
    for (int row = 0; row < 64; ++row) {
        int f = fragS[row];
        if (f != curF) {
            int gs = offs[curF], n = cnt[curF];
            if (gs >= r0 && gs + n <= r0 + 64) {
                ssum[(size_t)curF * HD + cc] = sAcc;
                nsum[(size_t)curF * HD + cc] = nAcc;
            } else {
                atomicAdd(&ssum[(size_t)curF * HD + cc], sAcc);
                atomicAdd(&nsum[(size_t)curF * HD + cc], nAcc);
            }
            sAcc = 0.f; nAcc = 0.f; curF = f;
        }
        float v = b2f(featS[row * 256 + (cc ^ ((row & 7) << 2))]);
        sAcc += v;
        nAcc = fmaf(v, rnS[row], nAcc);
    }
    {
        int gs = offs[curF], n = cnt[curF];
        if (gs >= r0 && gs + n <= r0 + 64) {
            ssum[(size_t)curF * HD + cc] = sAcc;
            nsum[(size_t)curF * HD + cc] = nAcc;
        } else {
            atomicAdd(&ssum[(size_t)curF * HD + cc], sAcc);
            atomicAdd(&nsum[(size_t)curF * HD + cc], nAcc);
        }
    }
}

// ---------------- fragment pass ----------------
__global__ __launch_bounds__(256) void k_frag(
    const float* __restrict__ ssum, const float* __restrict__ nsum,
    const int* __restrict__ cnt, const float* __restrict__ vsum,
    const float* __restrict__ vfsum, const float* __restrict__ nvsum,
    double* __restrict__ dbl) {
    int gwave = (blockIdx.x * blockDim.x + threadIdx.x) >> 6;
    int lane = threadIdx.x & 63;
    int nw = (gridDim.x * blockDim.x) >> 6;

    double la0 = 0, la1 = 0, la2 = 0, la3 = 0;
    double lv = 0, ltr = 0, lvc = 0, ldS = 0, ldV = 0;

    for (int f = gwave; f < NF; f += nw) {
        float4 s = ((const float4*)(ssum + (size_t)f * HD))[lane];
        float4 nn = ((const float4*)(nsum + (size_t)f * HD))[lane];
        int c = cnt[f];
        float ssq = s.x * s.x + s.y * s.y + s.z * s.z + s.w * s.w;
        float dsn = nn.x * s.x + nn.y * s.y + nn.z * s.z + nn.w * s.w;
#pragma unroll
        for (int m = 32; m; m >>= 1) {
            ssq += __shfl_xor(ssq, m, 64);
            dsn += __shfl_xor(dsn, m, 64);
        }
        float inv_all = 1.f / fmaxf((float)c, 1.f);
        float m0 = s.x * inv_all, m1 = s.y * inv_all, m2 = s.z * inv_all, m3 = s.w * inv_all;
        float ssq_mean = ssq * inv_all * inv_all;
        float vfr = vsum[f] * inv_all;
        float nrm2 = ssq_mean + vfr * vfr;
        float inv = 1.f / fmaxf(sqrtf(nrm2), NEPS);
        la0 += (double)(m0 * inv);
        la1 += (double)(m1 * inv);
        la2 += (double)(m2 * inv);
        la3 += (double)(m3 * inv);
        if (lane == 0) {
            lv += (double)(vfr * inv);
            ltr += (double)(nrm2 * inv * inv);
            if (c >= MINFRAG) {
                lvc += (double)c;
                float denom = fmaxf(sqrtf(ssq), NEPS);
                ldS += (double)c - (double)(dsn / denom);
                float vfm = vfsum[f] * inv_all;
                float vsgn = vfm / fmaxf(fabsf(vfm), NEPS);
                ldV += (double)c - (double)(vsgn * nvsum[f]);
            }
        }
    }
    atomicAdd(&dbl[4 * lane + 0], la0);
    atomicAdd(&dbl[4 * lane + 1], la1);
    atomicAdd(&dbl[4 * lane + 2], la2);
    atomicAdd(&dbl[4 * lane + 3], la3);
    if (lane == 0) {
        atomicAdd(&dbl[256], lv);
        atomicAdd(&dbl[IDX_TRACE], ltr);
        atomicAdd(&dbl[IDX_VCNT], lvc);
        atomicAdd(&dbl[IDX_DEVS], ldS);
        atomicAdd(&dbl[IDX_DEVV], ldV);
    }
}

// ---------------- final combine ----------------
__global__ __launch_bounds__(64) void k_final(const double* __restrict__ dbl,
                                              float* __restrict__ out) {
    if (threadIdx.x == 0 && blockIdx.x == 0) {
        double s2 = 0;
        for (int d = 0; d < 257; ++d) s2 += dbl[d] * dbl[d];
        double off = s2 - dbl[IDX_TRACE];
        double inter = off / ((double)NF * NF - NF + 1e-6);
        double vc = fmax(dbl[IDX_VCNT], 1.0);
        double total = dbl[IDX_DEVS] / vc + dbl[IDX_DEVV] / vc + 0.2 * inter;
        out[0] = (float)(0.03 * 0.05 * total);
    }
}

extern "C" void kernel_launch(void* const* d_in, const int* in_sizes, int n_in,
                              void* d_out, int out_size, void* d_ws, size_t ws_size,
                              hipStream_t stream) {
    const float* scalar_short = (const float*)d_in[0];
    const float* vector_short = (const float*)d_in[2];
    const int* fragment_ids = (const int*)d_in[4];
    const float* ln_gamma = (const float*)d_in[5];
    const float* ln_beta = (const float*)d_in[6];
    const float* W1 = (const float*)d_in[7];
    const float* b1 = (const float*)d_in[8];
    const float* Wv = (const float*)d_in[9];
    float* out = (float*)d_out;

    char* ws = (char*)d_ws;
    int* cnt = (int*)(ws + OFF_CNT);
    float* vsum = (float*)(ws + OFF_VSUM);
    float* vfsum = (float*)(ws + OFF_VFSUM);
    float* nvsum = (float*)(ws + OFF_NVSUM);
    int* fill = (int*)(ws + OFF_FILL);
    double* dbl = (double*)(ws + OFF_DBL);
    float* ssum = (float*)(ws + OFF_SSUM);
    float* nsum = (float*)(ws + OFF_NSUM);
    int* offs = (int*)(ws + OFF_OFFS);
    float* svec = (float*)(ws + OFF_SVEC);
    float* c0 = (float*)(ws + OFF_C0);
    float* w0 = (float*)(ws + OFF_W0);
    unsigned short* Gbf = (unsigned short*)(ws + OFF_GBF);
    int* order = (int*)(ws + OFF_ORDER);

    hipMemsetAsync(ws, 0, ZERO_BYTES, stream);
    k_prep<<<HD + 1, 256, 0, stream>>>(W1, ln_gamma, ln_beta, b1, Wv, Gbf, svec, c0, w0);
    k_stats<<<2048, 256, 0, stream>>>(vector_short, fragment_ids, w0, cnt, vsum, vfsum, nvsum);
    k_scan<<<1, 256, 0, stream>>>(cnt, offs);
    k_scatter<<<NA / 256, 256, 0, stream>>>(fragment_ids, offs, fill, order);
    k_gemm<<<NA / 64, 256, 0, stream>>>(scalar_short, Gbf, svec, c0, order,
                                        fragment_ids, offs, cnt, ssum, nsum);
    k_frag<<<64, 256, 0, stream>>>(ssum, nsum, cnt, vsum, vfsum, nvsum, dbl);
    k_final<<<1, 64, 0, stream>>>(dbl, out);
}